// Round 1
// baseline (107.406 us; speedup 1.0000x reference)
//
#include <hip/hip_runtime.h>
#include <hip/hip_bf16.h>

// Shapes: A=256, M=16, T=80, O=64
// Inputs: targets(A,T,2) f32, target_mask(A,T) i32, traj_preds(A,M,T,4) f32,
//         mode_probs(A,M) f32 (UNUSED), agent_fut_width(A,T) f32,
//         other_fut_trajs(A,O,T,2) f32, other_fut_masks(A,O,T) i32,
//         other_fut_widths(A,O,T) f32
// Outputs (concat flat): total(A,M), collision_penalty(A,M), l2_penalty(A,M)
//
// collision[a,m] = #{ t : exists o with dist(pi[a,m,t], other[a,o,t]) <= radius
//                       and tm[a,t]>0 and omask[a,o,t]>0 }   (any over O, sum over T)
//
// Exactness: collide boolean must match numpy fp32 bit-exactly (quantum = 100,
// threshold = 37). All predicate math uses __f*_rn intrinsics (no fp-contract)
// and __fsqrt_rn (correctly rounded, == np.sqrt on float32).

#define T_DIM 80
#define M_DIM 16
#define O_DIM 64
#define TH 40   // half of T staged at a time (keeps LDS < 64 KB)

__global__ __launch_bounds__(256) void prc_kernel(
    const float* __restrict__ targets,      // (A,T,2)
    const int*   __restrict__ tmask,        // (A,T)
    const float* __restrict__ preds,        // (A,M,T,4)
    const float* __restrict__ afw,          // (A,T)
    const float* __restrict__ otraj,        // (A,O,T,2)
    const int*   __restrict__ omask,        // (A,O,T)
    const float* __restrict__ owid,         // (A,O,T)
    float* __restrict__ out, int A)
{
    const int a = blockIdx.x;
    const int tid = threadIdx.x;

    __shared__ float  tmS[T_DIM];
    __shared__ float  wiS[T_DIM];
    __shared__ float2 tgS[T_DIM];
    __shared__ float2 piS[T_DIM][M_DIM + 1];   // +1 pad: staging-write conflicts
    __shared__ float  oxS[O_DIM][TH + 1];      // +1 pad: main-loop read 2-way (free)
    __shared__ float  oyS[O_DIM][TH + 1];
    __shared__ float  raS[O_DIM][TH + 1];      // radius; -1 => invalid (tm==0 or omask==0)
    __shared__ float  l2S[4][M_DIM];
    __shared__ int    cnS[4][M_DIM];

    const float2* tg2 = (const float2*)targets;
    const float4* pr4 = (const float4*)preds;
    const float2* ot2 = (const float2*)otraj;

    // ---- Phase A: per-t scalars ----
    if (tid < T_DIM) {
        int t = tid;
        float tm = (float)tmask[a * T_DIM + t];   // mask in {0,1}
        tmS[t] = tm;
        wiS[t] = afw[a * T_DIM + t];
        float2 g = tg2[a * T_DIM + t];
        tgS[t] = make_float2(__fmul_rn(g.x, tm), __fmul_rn(g.y, tm));
    }
    __syncthreads();

    // ---- Phase B: masked predictions piS[t][m] ----
    #pragma unroll
    for (int k = 0; k < 5; ++k) {
        int i = tid + k * 256;            // i = m*80 + t, 0..1279
        int m = i / T_DIM;
        int t = i - m * T_DIM;
        float4 p = pr4[a * (M_DIM * T_DIM) + i];
        float tm = tmS[t];
        piS[t][m] = make_float2(__fmul_rn(p.x, tm), __fmul_rn(p.y, tm));
    }
    __syncthreads();

    // ---- Phase D: L2 partial sums (one wave; m x t-chunk) ----
    if (tid < 64) {
        int m = tid & 15, tc4 = tid >> 4;
        float acc = 0.0f;
        for (int tt = 0; tt < 20; ++tt) {
            int t = tc4 * 20 + tt;
            float2 p = piS[t][m];
            float2 g = tgS[t];
            float dx = __fsub_rn(p.x, g.x);
            float dy = __fsub_rn(p.y, g.y);
            float s  = __fadd_rn(__fmul_rn(dx, dx), __fmul_rn(dy, dy));
            acc = __fadd_rn(acc, __fsqrt_rn(s));   // sqrt(0)==0 == safe_norm
        }
        l2S[tc4][m] = acc;
    }

    // ---- Main: collision. thread = (o = tid&63, tc = tid>>6) ----
    const int o  = tid & 63;
    const int tc = tid >> 6;
    int ctr = 0;   // lane accumulates count for m = (tid & 15) over this wave's t's

    for (int h = 0; h < 2; ++h) {
        __syncthreads();   // previous half fully consumed / piS staged
        // stage other-agent half: j = o*40 + tl (coalesced global reads)
        #pragma unroll
        for (int k = 0; k < 10; ++k) {
            int j  = tid + k * 256;       // 0..2559
            int oo = j / TH;
            int tl = j - oo * TH;
            int t  = h * TH + tl;
            int gi = (a * O_DIM + oo) * T_DIM + t;
            float2 tr = ot2[gi];
            int   om = omask[gi];
            float wo = owid[gi];
            float tm = tmS[t];
            float rad = (tm != 0.0f && om > 0)
                      ? __fmul_rn(0.5f, __fadd_rn(wiS[t], wo))
                      : -1.0f;
            oxS[oo][tl] = tr.x;
            oyS[oo][tl] = tr.y;
            raS[oo][tl] = rad;
        }
        __syncthreads();

        for (int tt = 0; tt < 10; ++tt) {
            int tl = tc * 10 + tt;
            int t  = h * TH + tl;
            if (tmS[t] == 0.0f) continue;   // wave-uniform skip: whole t invalid
            float ox  = oxS[o][tl];
            float oy  = oyS[o][tl];
            float rad = raS[o][tl];
            unsigned mm = 0;
            #pragma unroll
            for (int m = 0; m < M_DIM; ++m) {
                float2 p = piS[t][m];       // uniform address -> LDS broadcast
                float dx = __fsub_rn(p.x, ox);
                float dy = __fsub_rn(p.y, oy);
                float s  = __fadd_rn(__fmul_rn(dx, dx), __fmul_rn(dy, dy));
                float dist = __fsqrt_rn(s); // bit-exact vs np.sqrt
                if (dist <= rad) mm |= (1u << m);   // rad=-1 => never
            }
            // any-over-O: OR the 16-bit m-masks across all 64 lanes
            int v = (int)mm;
            v |= __shfl_xor(v, 1, 64);
            v |= __shfl_xor(v, 2, 64);
            v |= __shfl_xor(v, 4, 64);
            v |= __shfl_xor(v, 8, 64);
            v |= __shfl_xor(v, 16, 64);
            v |= __shfl_xor(v, 32, 64);
            ctr += (v >> (tid & 15)) & 1;   // this t collides for m=(tid&15)
        }
    }
    if ((tid & 63) < 16) cnS[tc][tid & 15] = ctr;
    __syncthreads();

    // ---- Epilogue ----
    if (tid < M_DIM) {
        int m = tid;
        float tl2 = __fadd_rn(__fadd_rn(__fadd_rn(l2S[0][m], l2S[1][m]),
                                        l2S[2][m]), l2S[3][m]);
        int cnt = cnS[0][m] + cnS[1][m] + cnS[2][m] + cnS[3][m];
        float l2p = __fsub_rn(8.0f, tl2);                 // -(total_l2 - 8)
        float cp  = __fmul_rn(-100.0f, (float)cnt);
        int AM = A * M_DIM;
        out[a * M_DIM + m]          = __fadd_rn(l2p, cp); // total
        out[AM + a * M_DIM + m]     = cp;                 // collision_penalty
        out[2 * AM + a * M_DIM + m] = l2p;                // l2_penalty
    }
}

extern "C" void kernel_launch(void* const* d_in, const int* in_sizes, int n_in,
                              void* d_out, int out_size, void* d_ws, size_t ws_size,
                              hipStream_t stream) {
    const float* targets = (const float*)d_in[0];
    const int*   tmask   = (const int*)  d_in[1];
    const float* preds   = (const float*)d_in[2];
    // d_in[3] = mode_probs: unused by the reference
    const float* afw     = (const float*)d_in[4];
    const float* otraj   = (const float*)d_in[5];
    const int*   omask   = (const int*)  d_in[6];
    const float* owid    = (const float*)d_in[7];
    float* out = (float*)d_out;

    int A = in_sizes[1] / T_DIM;   // target_mask is (A,T)

    prc_kernel<<<A, 256, 0, stream>>>(targets, tmask, preds, afw,
                                      otraj, omask, owid, out, A);
}

// Round 2
// 91.086 us; speedup vs baseline: 1.1792x; 1.1792x over previous
//
#include <hip/hip_runtime.h>
#include <hip/hip_bf16.h>
#include <math.h>

// Shapes: A=256, M=16, T=80, O=64
// Outputs (concat flat): total(A,M), collision_penalty(A,M), l2_penalty(A,M)
//
// collision[a,m] = #{ t : any_o [ dist(pi[a,m,t], other[a,o,t]) <= radius
//                                  && tm[a,t]>0 && omask[a,o,t]>0 ] }
//
// Exact sqrt-free predicate: rn(sqrt(s)) <= rad  <=>  s <= r2f, where
//   thr  = midpoint(rad, nextafterf(rad,+inf))   (exact in double; 25-bit odd mantissa)
//   thr2 = thr*thr                               (<=50 bits: exact in double; never a float)
//   r2f  = largest float < thr2
// This is bit-equivalent to numpy fp32 semantics; no per-element sqrt needed.

#define T_DIM 80
#define M_DIM 16
#define O_DIM 64
#define TH 40      // half of T staged per pass (keeps LDS < 64 KB)
#define NW 16      // waves per block (1024 threads)

__global__ __launch_bounds__(1024) void prc_kernel(
    const float* __restrict__ targets,      // (A,T,2)
    const int*   __restrict__ tmask,        // (A,T)
    const float* __restrict__ preds,        // (A,M,T,4)
    const float* __restrict__ afw,          // (A,T)
    const float* __restrict__ otraj,        // (A,O,T,2)
    const int*   __restrict__ omask,        // (A,O,T)
    const float* __restrict__ owid,         // (A,O,T)
    float* __restrict__ out, int A)
{
    const int a    = blockIdx.x;
    const int tid  = threadIdx.x;
    const int lane = tid & 63;
    const int w    = tid >> 6;

    __shared__ float  tmS[T_DIM];
    __shared__ float  wiS[T_DIM];
    __shared__ float2 tgS[T_DIM];
    __shared__ float2 piS[T_DIM][M_DIM + 1];   // masked preds, [t][m]
    __shared__ float  oxS[O_DIM][TH + 1];      // stride 41: (o*41)%32 hits all banks
    __shared__ float  oyS[O_DIM][TH + 1];
    __shared__ float  r2S[O_DIM][TH + 1];      // exact sqrt-free threshold; -1 = invalid
    __shared__ float  l2S[16][M_DIM + 1];
    __shared__ int    cnW[NW][M_DIM];

    const float2* tg2 = (const float2*)targets;
    const float4* pr4 = (const float4*)preds;
    const float2* ot2 = (const float2*)otraj;

    // ---- Phase A: per-t scalars ----
    if (tid < T_DIM) {
        int t = tid;
        float tm = (float)tmask[a * T_DIM + t];
        tmS[t] = tm;
        wiS[t] = afw[a * T_DIM + t];
        float2 g = tg2[a * T_DIM + t];
        tgS[t] = make_float2(__fmul_rn(g.x, tm), __fmul_rn(g.y, tm));
    }
    __syncthreads();   // tmS/wiS ready for all staging

    // ---- Phase B: masked predictions piS[t][m] (1280 float4) ----
    #pragma unroll
    for (int k = 0; k < 2; ++k) {
        int i = tid + k * 1024;
        if (i < M_DIM * T_DIM) {
            int m = i / T_DIM;
            int t = i - m * T_DIM;
            float4 p = pr4[a * (M_DIM * T_DIM) + i];
            float tm = tmS[t];
            piS[t][m] = make_float2(__fmul_rn(p.x, tm), __fmul_rn(p.y, tm));
        }
    }

    int cnt[M_DIM];
    #pragma unroll
    for (int m = 0; m < M_DIM; ++m) cnt[m] = 0;

    for (int h = 0; h < 2; ++h) {
        if (h) __syncthreads();   // previous half fully consumed
        // ---- Stage other-agent half h: j = oo*40 + tl (coalesced) ----
        #pragma unroll
        for (int k = 0; k < 3; ++k) {
            int j = tid + k * 1024;
            if (j < O_DIM * TH) {
                int oo = j / TH;
                int tl = j - oo * TH;
                int t  = h * TH + tl;
                int gi = (a * O_DIM + oo) * T_DIM + t;
                float2 tr = ot2[gi];
                int   om = omask[gi];
                float wo = owid[gi];
                float tm = tmS[t];
                float r2 = -1.0f;
                if (tm != 0.0f && om > 0) {
                    float rad = __fmul_rn(0.5f, __fadd_rn(wiS[t], wo));
                    float nxt = nextafterf(rad, __builtin_inff());
                    double thr  = 0.5 * ((double)rad + (double)nxt); // exact midpoint
                    double thr2 = thr * thr;                         // exact (<=50 bits)
                    float f = (float)thr2;
                    if ((double)f > thr2) f = nextafterf(f, -__builtin_inff());
                    r2 = f;   // largest float < thr2
                }
                oxS[oo][tl] = tr.x;
                oyS[oo][tl] = tr.y;
                r2S[oo][tl] = r2;
            }
        }
        __syncthreads();   // piS (h==0) + others staged

        // ---- L2 partial sums, first pass only (waves 0-3) ----
        if (h == 0 && tid < 256) {
            int m = tid & 15, tq = tid >> 4;
            float acc = 0.0f;
            #pragma unroll
            for (int tt = 0; tt < 5; ++tt) {
                int t = tq * 5 + tt;
                float2 p = piS[t][m];
                float2 g = tgS[t];
                float dx = __fsub_rn(p.x, g.x);
                float dy = __fsub_rn(p.y, g.y);
                float s  = __fadd_rn(__fmul_rn(dx, dx), __fmul_rn(dy, dy));
                acc = __fadd_rn(acc, __fsqrt_rn(s));
            }
            l2S[tq][m] = acc;
        }

        // ---- Collision: lane = o, wave strides t ----
        for (int tl = w; tl < TH; tl += NW) {
            int t = h * TH + tl;
            if (tmS[t] == 0.0f) continue;        // wave-uniform skip
            float ox = oxS[lane][tl];
            float oy = oyS[lane][tl];
            float r2 = r2S[lane][tl];
            #pragma unroll
            for (int m = 0; m < M_DIM; ++m) {
                float2 p = piS[t][m];            // uniform address -> broadcast
                float dx = __fsub_rn(p.x, ox);
                float dy = __fsub_rn(p.y, oy);
                float s  = __fadd_rn(__fmul_rn(dx, dx), __fmul_rn(dy, dy));
                unsigned long long b = __ballot(s <= r2);  // any over O (64 lanes)
                cnt[m] += (b != 0ull) ? 1 : 0;   // wave-uniform scalar add
            }
        }
    }

    // ---- Per-wave counts -> LDS (values are wave-uniform) ----
    if (lane == 0) {
        #pragma unroll
        for (int m = 0; m < M_DIM; ++m) cnW[w][m] = cnt[m];
    }
    __syncthreads();

    // ---- Epilogue ----
    if (tid < M_DIM) {
        int m = tid;
        float tl2 = 0.0f;
        #pragma unroll
        for (int j = 0; j < 16; ++j) tl2 = __fadd_rn(tl2, l2S[j][m]);
        int c = 0;
        #pragma unroll
        for (int j = 0; j < NW; ++j) c += cnW[j][m];
        float l2p = __fsub_rn(8.0f, tl2);                 // -(total_l2 - 8)
        float cp  = __fmul_rn(-100.0f, (float)c);
        int AM = A * M_DIM;
        out[a * M_DIM + m]          = __fadd_rn(l2p, cp);
        out[AM + a * M_DIM + m]     = cp;
        out[2 * AM + a * M_DIM + m] = l2p;
    }
}

extern "C" void kernel_launch(void* const* d_in, const int* in_sizes, int n_in,
                              void* d_out, int out_size, void* d_ws, size_t ws_size,
                              hipStream_t stream) {
    const float* targets = (const float*)d_in[0];
    const int*   tmask   = (const int*)  d_in[1];
    const float* preds   = (const float*)d_in[2];
    // d_in[3] = mode_probs: unused by the reference
    const float* afw     = (const float*)d_in[4];
    const float* otraj   = (const float*)d_in[5];
    const int*   omask   = (const int*)  d_in[6];
    const float* owid    = (const float*)d_in[7];
    float* out = (float*)d_out;

    int A = in_sizes[1] / T_DIM;   // target_mask is (A,T)

    prc_kernel<<<A, 1024, 0, stream>>>(targets, tmask, preds, afw,
                                       otraj, omask, owid, out, A);
}